// Round 10
// baseline (241.917 us; speedup 1.0000x reference)
//
#include <hip/hip_runtime.h>
#include <hip/hip_bf16.h>

// GVPDynamicProjection: N=10000, C=2, SI=128, VI=16, H=4, R=32, SH=32, VH=4
// R23 = R19-best everywhere (kA = R16 exact ~47us; kAttn = R19; kSmall
// unchanged; kAccum back to 800 blocks) + kAccum's atomic merge replaced by
// a TWO-STAGE reduction. Evidence: R22 (2x blocks = 2x atomics, half chain)
// cost +3.8us -> atomic tail A = 3.8 + L/2 > 0; 2.25M atomicAdds onto 11.5K
// addresses ~ 200 serialized RMW/addr. Stage 1 (kAccumP, 800 blocks, same
// math order) writes per-chunk partials with plain coalesced stores into
// part[200][64][180] (9.2MB at ws+2.7M floats; ws >= 256MB per R18 fill
// WRITE_SIZE). Stage 2 (kAccumR, 64x192) sums 200 chunks/row, ~4us.
// kA keeps its (now-dead) sg zeroing to stay byte-identical to R16.

#define N_  10000
#define C_  2
#define SI_ 128
#define VI_ 16
#define H_  4
#define R_  32
#define SH_ 32
#define VH_ 4
#define NC_ (N_*C_)

#define ROWS_ 16
#define XSTR_ 20   // XT leading stride: 16 rows + 4 pad; 80B = 5x16B aligned

typedef const float* __restrict__ fptr;

__device__ __forceinline__ float sigm(float x){ return 1.f/(1.f+__expf(-x)); }

// ---------------- ws layout (float offsets) ----------------
// pexp : [C_*32][N_]   exp(logits), TRANSPOSED      640000
// eqh  : [NC_][100]    per-row eq[4] @0, qh[96] @8  2000000
// sg   : [64][180]     final normalized-sum inputs (written by kAccumR)
// tkh/tek/tvs/tvv: attn tables
// part : [200][64][180] kAccum partials             2700000 (9.2MB)
#define OFF_LG   0
#define OFF_EQH  640000
#define OFF_SG   2640000
#define OFF_TKH  2651520
#define OFF_TEK  2657664
#define OFF_TVS  2657920
#define OFF_TVV  2666112
#define OFF_PART 2700000

#define SGSTRIDE_ 180
#define NCHUNK_   200

// ================= kernel A: per-row logits + q-path (R16 exact) ===========
// 256 threads, 16 rows/block; grid = NC_/16 = 1250; ~30.5KB LDS -> 5 blk/CU
__global__ __launch_bounds__(256) void kA(
    fptr s, fptr v,
    fptr wp_wh, fptr wp_ws_w, fptr wp_ws_b,
    fptr q_wh, fptr q_ws_w, fptr q_ws_b, fptr q_wv, fptr q_wsv_w, fptr q_wsv_b,
    fptr attn_wh, fptr attn_ws_w,
    float* __restrict__ pexp, float* __restrict__ eqh,
    float* __restrict__ sgz)
{
  // ARENA: phase 0-2 = XT transposed [j][row], stride 20 (16B-aligned:
  //        j*80B = 5x16B; rgA*8 floats = 32B)
  //        j: 0..127 = s, 128..143 = vn_q, 144..159 = vn_p
  //        phase 2c+ = SIG [16][128] (2048 <= 3200), aliases dead XT
  __shared__ __align__(16) float ARENA[160*XSTR_];
  __shared__ __align__(16) float VVs[ROWS_*48];
  __shared__ __align__(16) float VHQ[ROWS_*48];
  __shared__ __align__(16) float SO[ROWS_*128];
  __shared__ __align__(16) float GATE[ROWS_*16];
  __shared__ __align__(16) float QV[ROWS_*48];
  float* const XT  = ARENA;
  float* const SIG = ARENA;

  const int tid  = threadIdx.x;
  const int row0 = blockIdx.x * ROWS_;

  // block 0 zeroes sg (dead after R23's two-stage kAccum, kept so kA stays
  // byte-identical to the proven R16 body)
  if (blockIdx.x == 0){
    for (int i = tid; i < 64*SGSTRIDE_; i += 256) sgz[i] = 0.f;
  }

  // phase 0: stage s, v
  for (int idx = tid; idx < ROWS_*128; idx += 256){
    int r = idx >> 7, j = idx & 127;
    XT[j*XSTR_ + r] = s[(row0+r)*128 + j];
  }
  for (int idx = tid; idx < ROWS_*48; idx += 256){
    int r = idx / 48, k = idx - r*48;
    VVs[r*48 + k] = v[(row0+r)*48 + k];
  }
  __syncthreads();

  // phase 1: vh / vn, 16 rows x 32 (path,i) = 512 work items
  for (int idx = tid; idx < ROWS_*32; idx += 256){
    int r = idx >> 5, ii = idx & 31, path = ii >> 4, i = ii & 15;
    fptr wh = path ? wp_wh : q_wh;
    float h0=0.f, h1=0.f, h2=0.f;
    #pragma unroll
    for (int j = 0; j < 16; j++){
      float w = wh[j*16 + i];
      h0 = fmaf(VVs[r*48 + j*3 + 0], w, h0);
      h1 = fmaf(VVs[r*48 + j*3 + 1], w, h1);
      h2 = fmaf(VVs[r*48 + j*3 + 2], w, h2);
    }
    float vn = sqrtf(fmaxf(h0*h0 + h1*h1 + h2*h2, 1e-8f));
    if (!path){
      VHQ[r*48 +  0 + i] = h0;
      VHQ[r*48 + 16 + i] = h1;
      VHQ[r*48 + 32 + i] = h2;
      XT[(128+i)*XSTR_ + r] = vn;
    } else {
      XT[(144+i)*XSTR_ + r] = vn;
    }
  }
  __syncthreads();

  // phase 2a: so = [s, vn_q] @ q_ws_w + b  (128 cols x 2 rowgroups of 8 rows)
  const int colA = tid & 127, rgA = tid >> 7;   // rgA in {0,1}, 8 rows each
  float acc[8];
  {
    float bqs = q_ws_b[colA];
    #pragma unroll
    for (int k = 0; k < 8; k++) acc[k] = bqs;
    const float* xbA = &XT[rgA*8];
    #pragma unroll 8
    for (int j = 0; j < 144; j++){
      float w = q_ws_w[j*128 + colA];             // coalesced 64-consec/wave
      const float* xb = xbA + j*XSTR_;
      float4 x0 = *(const float4*)(xb + 0);       // wave-uniform broadcast
      float4 x1 = *(const float4*)(xb + 4);
      acc[0] = fmaf(x0.x, w, acc[0]); acc[1] = fmaf(x0.y, w, acc[1]);
      acc[2] = fmaf(x0.z, w, acc[2]); acc[3] = fmaf(x0.w, w, acc[3]);
      acc[4] = fmaf(x1.x, w, acc[4]); acc[5] = fmaf(x1.y, w, acc[5]);
      acc[6] = fmaf(x1.z, w, acc[6]); acc[7] = fmaf(x1.w, w, acc[7]);
    }
  }
  // phase 2b: logits -> store EXP(logit), TRANSPOSED pexp[(c*32+a)][n]
  // 32 cols x 8 rowgroups of 2 rows
  {
    const int colB = tid & 31, rgB = tid >> 5;    // rgB in [0,8), 2 rows each
    float b0 = wp_ws_b[colB];
    float a0 = b0, a1 = b0;
    #pragma unroll 8
    for (int j = 0; j < 144; j++){
      int jj = (j < 128) ? j : (j + 16);
      float w = wp_ws_w[j*32 + colB];
      const float* xb = &XT[jj*XSTR_ + rgB*2];
      a0 = fmaf(xb[0], w, a0);
      a1 = fmaf(xb[1], w, a1);
    }
    // rows row0 + rgB*2 + {0,1}; row0 multiple of 16 -> c = k, n = row0/2+rgB
    const int n = (row0 >> 1) + rgB;
    pexp[(0*32 + colB)*N_ + n] = __expf(a0);      // c=0  (no max-sub: |l|<~8)
    pexp[(1*32 + colB)*N_ + n] = __expf(a1);      // c=1
  }
  __syncthreads();                                // XT dead; SIG live

  // phase 2c: sig/silu once from registers
  #pragma unroll
  for (int k = 0; k < 8; k++){
    float so = acc[k];
    float sg_ = sigm(so);
    SIG[(rgA*8 + k)*128 + colA] = sg_;
    SO [(rgA*8 + k)*128 + colA] = so * sg_;       // silu
  }
  __syncthreads();

  // phase 3: gate = sigmoid(sig_so @ q_wsv_w + b)  (16 rows x 16 = 256 thr)
  {
    const int r = tid >> 4, g = tid & 15;
    float ga = q_wsv_b[g];
    #pragma unroll 8
    for (int o = 0; o < 128; o += 4){
      float4 s4 = *(const float4*)&SIG[r*128 + o];
      ga = fmaf(s4.x, q_wsv_w[(o+0)*16 + g], ga);
      ga = fmaf(s4.y, q_wsv_w[(o+1)*16 + g], ga);
      ga = fmaf(s4.z, q_wsv_w[(o+2)*16 + g], ga);
      ga = fmaf(s4.w, q_wsv_w[(o+3)*16 + g], ga);
    }
    GATE[r*16 + g] = sigm(ga);
  }
  __syncthreads();

  // phase 4 (64 items) + phase 5 (768 items) combined strided loop
  for (int t = tid; t < 64 + ROWS_*48; t += 256){
    if (t < 64){
      // eq[h] = silu_so_head . ws_q   (16 rows x 4 h)
      const int r = t >> 2, h = t & 3;
      float e = 0.f;
      #pragma unroll
      for (int u = 0; u < 32; u++)
        e = fmaf(SO[r*128 + h*32 + u], attn_ws_w[u], e);
      eqh[(row0 + r)*100 + h] = e;
    } else {
      // qv = (vh_q @ q_wv)^T * gate   (16*48 = 768 work items)
      const int t2 = t - 64;
      int r = t2 / 48, k = t2 - r*48, i = k / 3, d = k - i*3;
      float a = 0.f;
      #pragma unroll
      for (int j = 0; j < 16; j++)
        a = fmaf(VHQ[r*48 + d*16 + j], q_wv[j*16 + i], a);
      QV[r*48 + k] = a * GATE[r*16 + i];
    }
  }
  __syncthreads();

  // phase 6: qh[h][d][e] = sum_i qv[h*4+i][d] * wh_q[i][e]  (16*96 = 1536)
  for (int t = tid; t < ROWS_*96; t += 256){
    int r = t / 96, k = t - r*96;
    int h = k / 24, rem = k - h*24, d = rem >> 3, ee = rem & 7;
    float a = 0.f;
    #pragma unroll
    for (int i = 0; i < 4; i++)
      a = fmaf(QV[r*48 + (h*4 + i)*3 + d], attn_wh[i*8 + ee], a);
    eqh[(row0 + r)*100 + 8 + k] = a;
  }
}

// ===== kAccumP: stage 1 — per-chunk partial sums, plain stores =============
// 800 blocks = (chunk 200) x (ah 2) x (c 2); 50 n per chunk. Same thread
// layout and in-block math order as the R13 atomic version.
__global__ __launch_bounds__(256) void kAccumP(const float* __restrict__ pexp,
                                               fptr s, fptr v,
                                               float* __restrict__ part)
{
  const int b = blockIdx.x;
  const int c = b & 1, ah = (b >> 1) & 1, chunk = b >> 2;   // chunk [0,200)
  const int n0 = chunk * 50;
  const int tid = threadIdx.x;
  const int ag = tid >> 6, dl = tid & 63;
  const int abase = ah*16 + ag*4;

  const float* pb = pexp + (c*32 + abase)*N_;
  float acc[4][3] = {};
  float dn[4] = {};

  #pragma unroll 2
  for (int n = n0; n < n0 + 50; n++){
    const int rc = n*2 + c;
    float pw[4];
    #pragma unroll
    for (int aa = 0; aa < 4; aa++){
      pw[aa] = pb[aa*N_ + n];
      dn[aa] += pw[aa];
    }
    #pragma unroll
    for (int dd = 0; dd < 3; dd++){
      int d = dl + 64*dd;
      if (d < 176){
        float xv = (d < 128) ? s[rc*128 + d] : v[rc*48 + d - 128];
        #pragma unroll
        for (int aa = 0; aa < 4; aa++)
          acc[aa][dd] = fmaf(pw[aa], xv, acc[aa][dd]);
      }
    }
  }
  float* pout = part + (size_t)chunk*(64*SGSTRIDE_);
  #pragma unroll
  for (int aa = 0; aa < 4; aa++){
    const int base = (c*32 + abase + aa)*SGSTRIDE_;
    #pragma unroll
    for (int dd = 0; dd < 3; dd++){
      int d = dl + 64*dd;
      if (d < 176) pout[base + d] = acc[aa][dd];
    }
    if (dl == 0) pout[base + 176] = dn[aa];
  }
}

// ===== kAccumR: stage 2 — reduce 200 chunks per sg row =====================
// 64 blocks (one per sg row) x 192 threads (d < 177 active). Loads are
// independent (200-deep, stride 46KB) -> fully pipelined; writes sg with =.
__global__ __launch_bounds__(192) void kAccumR(const float* __restrict__ part,
                                               float* __restrict__ sg)
{
  const int row = blockIdx.x;
  const int d   = threadIdx.x;
  if (d > 176) return;
  const float* p = part + row*SGSTRIDE_ + d;
  float ssum = 0.f;
  #pragma unroll 4
  for (int ch = 0; ch < NCHUNK_; ch++)
    ssum += p[(size_t)ch*(64*SGSTRIDE_)];
  sg[row*SGSTRIDE_ + d] = ssum;
}

// ================= kSmall: normalize + k/vv GVP + attn tables ===============
__global__ __launch_bounds__(256) void kSmall(
    const float* __restrict__ sg,
    fptr k_wh, fptr k_ws_w, fptr k_ws_b, fptr k_wv, fptr k_wsv_w, fptr k_wsv_b,
    fptr vv_wh, fptr vv_ws_w, fptr vv_ws_b, fptr vv_wv, fptr vv_wsv_w, fptr vv_wsv_b,
    fptr attn_wh, fptr attn_ws_w,
    float* __restrict__ tkh, float* __restrict__ tek,
    float* __restrict__ tvs, float* __restrict__ tvv)
{
  const int b = blockIdx.x, r = b >> 1, c = b & 1;
  const int tid = threadIdx.x;
  __shared__ float X[176];
  __shared__ float VN[2][16];
  __shared__ float VH[2][48];
  __shared__ float SOk[128], SOv[128];
  __shared__ float G[2][16];
  __shared__ float KV[48];

  if (tid < 176){
    const float* p = sg + (c*32 + r)*SGSTRIDE_;
    X[tid] = p[tid] / p[176];
  }
  __syncthreads();

  if (tid < 32){
    int path = tid >> 4, i = tid & 15;
    fptr wh = path ? vv_wh : k_wh;
    float h0=0.f, h1=0.f, h2=0.f;
    #pragma unroll
    for (int j = 0; j < 16; j++){
      float w = wh[j*16 + i];
      h0 = fmaf(X[128 + j*3 + 0], w, h0);
      h1 = fmaf(X[128 + j*3 + 1], w, h1);
      h2 = fmaf(X[128 + j*3 + 2], w, h2);
    }
    VH[path][ 0 + i] = h0; VH[path][16 + i] = h1; VH[path][32 + i] = h2;
    VN[path][i] = sqrtf(fmaxf(h0*h0 + h1*h1 + h2*h2, 1e-8f));
  }
  __syncthreads();

  {
    int path = tid >> 7, col = tid & 127;
    fptr W  = path ? vv_ws_w : k_ws_w;
    fptr Bb = path ? vv_ws_b : k_ws_b;
    float so = Bb[col];
    for (int j = 0; j < 128; j++) so = fmaf(X[j], W[j*128 + col], so);
    #pragma unroll
    for (int i = 0; i < 16; i++)  so = fmaf(VN[path][i], W[(128+i)*128 + col], so);
    (path ? SOv : SOk)[col] = so;
  }
  __syncthreads();

  if (tid < 32){
    int path = tid >> 4, g = tid & 15;
    fptr Wsv = path ? vv_wsv_w : k_wsv_w;
    fptr Bsv = path ? vv_wsv_b : k_wsv_b;
    const float* SOp = path ? SOv : SOk;
    float ga = Bsv[g];
    for (int o = 0; o < 128; o++)
      ga = fmaf(sigm(SOp[o]), Wsv[o*16 + g], ga);
    G[path][g] = sigm(ga);
  } else if (tid < 36){
    int h = tid - 32;
    float e = 0.f;
    #pragma unroll
    for (int t = 0; t < 32; t++){
      float so = SOk[h*32 + t];
      e = fmaf(so * sigm(so), attn_ws_w[32 + t], e);
    }
    tek[(r*2 + c)*4 + h] = e;
  } else if (tid >= 64 && tid < 192){
    int o = tid - 64;
    float so = SOv[o];
    tvs[(r*2 + c)*128 + o] = so * sigm(so);
  }
  __syncthreads();

  if (tid < 96){
    int path = tid / 48, k = tid % 48, i = k / 3, d = k - i*3;
    fptr Wv = path ? vv_wv : k_wv;
    float vo = 0.f;
    #pragma unroll
    for (int j = 0; j < 16; j++)
      vo = fmaf(VH[path][d*16 + j], Wv[j*16 + i], vo);
    float gv = vo * G[path][i];
    if (path == 0) KV[k] = gv;
    else {
      int h = i >> 2, ii = i & 3;
      tvv[(((r*2 + c)*4 + h)*4 + ii)*3 + d] = gv;
    }
  }
  __syncthreads();

  if (tid < 96){
    int h = tid / 24, rem = tid % 24, d = rem >> 3, ee = rem & 7;
    float a = 0.f;
    #pragma unroll
    for (int i = 0; i < 4; i++)
      a = fmaf(KV[(h*4 + i)*3 + d], attn_wh[(4 + i)*8 + ee], a);
    tkh[((r*2 + c)*4 + h)*24 + d*8 + ee] = a;
  }
}

// ================= kAttn (R19): block = 64 rows x one h ====================
__global__ __launch_bounds__(256) void kAttn(
    const float* __restrict__ eqh,
    const float* __restrict__ tkh, const float* __restrict__ tek,
    const float* __restrict__ tvs, const float* __restrict__ tvv,
    fptr attn_ws_w, fptr attn_ws_b,
    float* __restrict__ out)
{
  __shared__ __align__(16) float KH[64*28];
  __shared__ __align__(16) float VS[64*36];
  __shared__ __align__(16) float VV[64*12];
  __shared__ float EK[64];
  const int tid = threadIdx.x;
  const int h      = blockIdx.x & 3;
  const int rowblk = blockIdx.x >> 2;

  for (int i = tid; i < 64*24; i += 256){
    int m = i / 24, t = i - m*24;
    KH[m*28 + t] = tkh[(m*4 + h)*24 + t];
  }
  for (int i = tid; i < 64*32; i += 256){
    int m = i >> 5, t = i & 31;
    VS[m*36 + t] = tvs[m*128 + h*32 + t];
  }
  for (int i = tid; i < 64*12; i += 256){
    int m = i / 12, t = i - m*12;
    VV[m*12 + t] = tvv[(m*4 + h)*12 + t];
  }
  if (tid < 64) EK[tid] = tek[tid*4 + h];

  float wsn[8];
  #pragma unroll
  for (int ee = 0; ee < 8; ee++) wsn[ee] = attn_ws_w[64 + ee];
  const float wb = attn_ws_b[0];
  __syncthreads();

  const int rh  = tid & 3;
  const int row = rowblk*64 + (tid >> 2);
  if (row < NC_){
    const int c = row & 1;
    const float eq = eqh[row*100 + h];
    float qh[24];
    {
      const float4* qp = (const float4*)&eqh[row*100 + 8 + h*24];
      #pragma unroll
      for (int k = 0; k < 6; k++){
        float4 t4 = qp[k];
        qh[k*4+0] = t4.x; qh[k*4+1] = t4.y; qh[k*4+2] = t4.z; qh[k*4+3] = t4.w;
      }
    }
    float4 accs4[8];
    float4 accv4[3];
    #pragma unroll
    for (int q = 0; q < 8; q++) accs4[q] = make_float4(0.f,0.f,0.f,0.f);
    #pragma unroll
    for (int q = 0; q < 3; q++) accv4[q] = make_float4(0.f,0.f,0.f,0.f);
    float den = 0.f;

    #pragma unroll
    for (int rr = 0; rr < 8; rr++){
      const int m = (rh*8 + rr)*2 + c;
      const float* khp = &KH[m*28];
      float en = 0.f;
      #pragma unroll
      for (int ee = 0; ee < 8; ee++){
        float a0 = qh[ee]      + khp[ee];
        float a1 = qh[8 + ee]  + khp[8 + ee];
        float a2 = qh[16 + ee] + khp[16 + ee];
        en = fmaf(sqrtf(fmaxf(a0*a0 + a1*a1 + a2*a2, 1e-8f)), wsn[ee], en);
      }
      const float w = __expf((eq + EK[m] + en + wb) * 0.17677669529663687f);
      den += w;
      const float4* vp4 = (const float4*)&VS[m*36];
      #pragma unroll
      for (int q = 0; q < 8; q++){
        float4 t4 = vp4[q];
        accs4[q].x = fmaf(w, t4.x, accs4[q].x);
        accs4[q].y = fmaf(w, t4.y, accs4[q].y);
        accs4[q].z = fmaf(w, t4.z, accs4[q].z);
        accs4[q].w = fmaf(w, t4.w, accs4[q].w);
      }
      const float4* vv4 = (const float4*)&VV[m*12];
      #pragma unroll
      for (int q = 0; q < 3; q++){
        float4 t4 = vv4[q];
        accv4[q].x = fmaf(w, t4.x, accv4[q].x);
        accv4[q].y = fmaf(w, t4.y, accv4[q].y);
        accv4[q].z = fmaf(w, t4.z, accv4[q].z);
        accv4[q].w = fmaf(w, t4.w, accv4[q].w);
      }
    }

    #pragma unroll
    for (int q = 0; q < 8; q++){
      accs4[q].x += __shfl_xor(accs4[q].x, 1, 64);
      accs4[q].x += __shfl_xor(accs4[q].x, 2, 64);
      accs4[q].y += __shfl_xor(accs4[q].y, 1, 64);
      accs4[q].y += __shfl_xor(accs4[q].y, 2, 64);
      accs4[q].z += __shfl_xor(accs4[q].z, 1, 64);
      accs4[q].z += __shfl_xor(accs4[q].z, 2, 64);
      accs4[q].w += __shfl_xor(accs4[q].w, 1, 64);
      accs4[q].w += __shfl_xor(accs4[q].w, 2, 64);
    }
    #pragma unroll
    for (int q = 0; q < 3; q++){
      accv4[q].x += __shfl_xor(accv4[q].x, 1, 64);
      accv4[q].x += __shfl_xor(accv4[q].x, 2, 64);
      accv4[q].y += __shfl_xor(accv4[q].y, 1, 64);
      accv4[q].y += __shfl_xor(accv4[q].y, 2, 64);
      accv4[q].z += __shfl_xor(accv4[q].z, 1, 64);
      accv4[q].z += __shfl_xor(accv4[q].z, 2, 64);
      accv4[q].w += __shfl_xor(accv4[q].w, 1, 64);
      accv4[q].w += __shfl_xor(accv4[q].w, 2, 64);
    }
    den += __shfl_xor(den, 1, 64);
    den += __shfl_xor(den, 2, 64);

    if (rh == 0){
      const float inv = 1.f / den;
      float4* po = (float4*)&out[row*128 + h*32];
      #pragma unroll
      for (int q = 0; q < 8; q++){
        float4 t4 = accs4[q];
        t4.x *= inv; t4.y *= inv; t4.z *= inv; t4.w *= inv;
        po[q] = t4;
      }
      float4* pv = (float4*)&out[NC_*128 + row*48 + h*12];
      #pragma unroll
      for (int q = 0; q < 3; q++){
        float4 t4 = accv4[q];
        t4.x *= inv; t4.y *= inv; t4.z *= inv; t4.w *= inv;
        pv[q] = t4;
      }
    }
  }
}

extern "C" void kernel_launch(void* const* d_in, const int* in_sizes, int n_in,
                              void* d_out, int out_size, void* d_ws, size_t ws_size,
                              hipStream_t stream)
{
  fptr s        = (fptr)d_in[0];
  fptr v        = (fptr)d_in[1];
  fptr wp_wh    = (fptr)d_in[2];
  fptr wp_ws_w  = (fptr)d_in[3];
  fptr wp_ws_b  = (fptr)d_in[4];
  fptr q_wh     = (fptr)d_in[5];
  fptr q_ws_w   = (fptr)d_in[6];
  fptr q_ws_b   = (fptr)d_in[7];
  fptr q_wv     = (fptr)d_in[8];
  fptr q_wsv_w  = (fptr)d_in[9];
  fptr q_wsv_b  = (fptr)d_in[10];
  fptr k_wh     = (fptr)d_in[11];
  fptr k_ws_w   = (fptr)d_in[12];
  fptr k_ws_b   = (fptr)d_in[13];
  fptr k_wv     = (fptr)d_in[14];
  fptr k_wsv_w  = (fptr)d_in[15];
  fptr k_wsv_b  = (fptr)d_in[16];
  fptr vv_wh    = (fptr)d_in[17];
  fptr vv_ws_w  = (fptr)d_in[18];
  fptr vv_ws_b  = (fptr)d_in[19];
  fptr vv_wv    = (fptr)d_in[20];
  fptr vv_wsv_w = (fptr)d_in[21];
  fptr vv_wsv_b = (fptr)d_in[22];
  fptr attn_wh  = (fptr)d_in[23];
  fptr attn_ws_w= (fptr)d_in[24];
  fptr attn_ws_b= (fptr)d_in[25];

  float* ws   = (float*)d_ws;
  float* pexp = ws + OFF_LG;
  float* eqh  = ws + OFF_EQH;
  float* sg   = ws + OFF_SG;
  float* tkh  = ws + OFF_TKH;
  float* tek  = ws + OFF_TEK;
  float* tvs  = ws + OFF_TVS;
  float* tvv  = ws + OFF_TVV;
  float* part = ws + OFF_PART;

  kA<<<NC_/ROWS_, 256, 0, stream>>>(s, v, wp_wh, wp_ws_w, wp_ws_b,
                                    q_wh, q_ws_w, q_ws_b, q_wv, q_wsv_w, q_wsv_b,
                                    attn_wh, attn_ws_w, pexp, eqh, sg);
  kAccumP<<<800, 256, 0, stream>>>(pexp, s, v, part);
  kAccumR<<<64, 192, 0, stream>>>(part, sg);
  kSmall<<<64, 256, 0, stream>>>(sg,
                                 k_wh, k_ws_w, k_ws_b, k_wv, k_wsv_w, k_wsv_b,
                                 vv_wh, vv_ws_w, vv_ws_b, vv_wv, vv_wsv_w, vv_wsv_b,
                                 attn_wh, attn_ws_w, tkh, tek, tvs, tvv);
  kAttn<<<((NC_ + 63)/64)*4, 256, 0, stream>>>(eqh, tkh, tek, tvs, tvv,
                                               attn_ws_w, attn_ws_b, (float*)d_out);
}

// Round 11
// 237.090 us; speedup vs baseline: 1.0204x; 1.0204x over previous
//
#include <hip/hip_runtime.h>
#include <hip/hip_bf16.h>

// GVPDynamicProjection: N=10000, C=2, SI=128, VI=16, H=4, R=32, SH=32, VH=4
// R24 = R19 pipeline (kAccum reverted to 800-block atomics: R22 +3.8us and
// R23 two-stage +8us proved the atomic tail is ~free) + ONE kA change:
// phase 2a remapped (wave = 4-row group, lane = 2 cols). Per j: ONE
// ds_read_b128 broadcast (4 rows) instead of two, w as coalesced float2.
// DS model (verified by R20's pipe-swap): 2a 13.8K -> 6.9K cyc/block,
// total 26.5K -> ~19.6K -> kA ~47 -> ~36us. FMA count/order, VMEM count,
// registers unchanged -> numerically identical, no new pipe pressure.
// Phases 0/1/2b/3/4/5/6 + kAccum/kSmall/kAttn byte-identical to R19.

#define N_  10000
#define C_  2
#define SI_ 128
#define VI_ 16
#define H_  4
#define R_  32
#define SH_ 32
#define VH_ 4
#define NC_ (N_*C_)

#define ROWS_ 16
#define XSTR_ 20   // XT leading stride: 16 rows + 4 pad; 80B = 5x16B aligned

typedef const float* __restrict__ fptr;

__device__ __forceinline__ float sigm(float x){ return 1.f/(1.f+__expf(-x)); }

// ---------------- ws layout (float offsets) ----------------
// pexp : [C_*32][N_]   exp(logits), TRANSPOSED      640000
// eqh  : [NC_][100]    per-row eq[4] @0, qh[96] @8  2000000
// sg   : [64][180]     sums: d<176 = sum e^l*x, 176 = sum e^l (zeroed by kA blk0)
// tkh/tek/tvs/tvv: attn tables
#define OFF_LG   0
#define OFF_EQH  640000
#define OFF_SG   2640000
#define OFF_TKH  2651520
#define OFF_TEK  2657664
#define OFF_TVS  2657920
#define OFF_TVV  2666112

#define SGSTRIDE_ 180

// ================= kernel A: per-row logits + q-path =================
// 256 threads, 16 rows/block; grid = NC_/16 = 1250; ~30.5KB LDS -> 5 blk/CU
__global__ __launch_bounds__(256) void kA(
    fptr s, fptr v,
    fptr wp_wh, fptr wp_ws_w, fptr wp_ws_b,
    fptr q_wh, fptr q_ws_w, fptr q_ws_b, fptr q_wv, fptr q_wsv_w, fptr q_wsv_b,
    fptr attn_wh, fptr attn_ws_w,
    float* __restrict__ pexp, float* __restrict__ eqh,
    float* __restrict__ sgz)
{
  // ARENA: phase 0-2 = XT transposed [j][row], stride 20 (16B-aligned:
  //        j*80B = 5x16B; rg4*4 floats = 16B)
  //        j: 0..127 = s, 128..143 = vn_q, 144..159 = vn_p
  //        phase 2c+ = SIG [16][128] (2048 <= 3200), aliases dead XT
  __shared__ __align__(16) float ARENA[160*XSTR_];
  __shared__ __align__(16) float VVs[ROWS_*48];
  __shared__ __align__(16) float VHQ[ROWS_*48];
  __shared__ __align__(16) float SO[ROWS_*128];
  __shared__ __align__(16) float GATE[ROWS_*16];
  __shared__ __align__(16) float QV[ROWS_*48];
  float* const XT  = ARENA;
  float* const SIG = ARENA;

  const int tid  = threadIdx.x;
  const int row0 = blockIdx.x * ROWS_;

  // block 0 also zeroes sg (kAccum is stream-ordered after all kA blocks)
  if (blockIdx.x == 0){
    for (int i = tid; i < 64*SGSTRIDE_; i += 256) sgz[i] = 0.f;
  }

  // phase 0: stage s, v
  for (int idx = tid; idx < ROWS_*128; idx += 256){
    int r = idx >> 7, j = idx & 127;
    XT[j*XSTR_ + r] = s[(row0+r)*128 + j];
  }
  for (int idx = tid; idx < ROWS_*48; idx += 256){
    int r = idx / 48, k = idx - r*48;
    VVs[r*48 + k] = v[(row0+r)*48 + k];
  }
  __syncthreads();

  // phase 1: vh / vn, 16 rows x 32 (path,i) = 512 work items
  for (int idx = tid; idx < ROWS_*32; idx += 256){
    int r = idx >> 5, ii = idx & 31, path = ii >> 4, i = ii & 15;
    fptr wh = path ? wp_wh : q_wh;
    float h0=0.f, h1=0.f, h2=0.f;
    #pragma unroll
    for (int j = 0; j < 16; j++){
      float w = wh[j*16 + i];
      h0 = fmaf(VVs[r*48 + j*3 + 0], w, h0);
      h1 = fmaf(VVs[r*48 + j*3 + 1], w, h1);
      h2 = fmaf(VVs[r*48 + j*3 + 2], w, h2);
    }
    float vn = sqrtf(fmaxf(h0*h0 + h1*h1 + h2*h2, 1e-8f));
    if (!path){
      VHQ[r*48 +  0 + i] = h0;
      VHQ[r*48 + 16 + i] = h1;
      VHQ[r*48 + 32 + i] = h2;
      XT[(128+i)*XSTR_ + r] = vn;
    } else {
      XT[(144+i)*XSTR_ + r] = vn;
    }
  }
  __syncthreads();

  // phase 2a (R24): wave rg4 = tid>>6 owns rows rg4*4..+3; lane owns 2 cols.
  // Per j: ONE b128 broadcast (4 rows) + one coalesced float2 w + 8 FMA.
  const int lane = tid & 63;
  const int rg4  = tid >> 6;          // rowgroup of 4 rows (= wave id)
  const int colP = lane*2;            // cols colP, colP+1
  float acc[4][2];
  {
    float2 bq = *(const float2*)&q_ws_b[colP];
    #pragma unroll
    for (int k = 0; k < 4; k++){ acc[k][0] = bq.x; acc[k][1] = bq.y; }
    const float* xbA = &XT[rg4*4];
    #pragma unroll 8
    for (int j = 0; j < 144; j++){
      float2 w2 = *(const float2*)&q_ws_w[j*128 + colP];  // 512B/wave contig
      float4 x4 = *(const float4*)(xbA + j*XSTR_);        // 4-row broadcast
      acc[0][0] = fmaf(x4.x, w2.x, acc[0][0]);
      acc[0][1] = fmaf(x4.x, w2.y, acc[0][1]);
      acc[1][0] = fmaf(x4.y, w2.x, acc[1][0]);
      acc[1][1] = fmaf(x4.y, w2.y, acc[1][1]);
      acc[2][0] = fmaf(x4.z, w2.x, acc[2][0]);
      acc[2][1] = fmaf(x4.z, w2.y, acc[2][1]);
      acc[3][0] = fmaf(x4.w, w2.x, acc[3][0]);
      acc[3][1] = fmaf(x4.w, w2.y, acc[3][1]);
    }
  }
  // phase 2b: logits -> store EXP(logit), TRANSPOSED pexp[(c*32+a)][n]
  // 32 cols x 8 rowgroups of 2 rows (byte-identical to R16/R19)
  {
    const int colB = tid & 31, rgB = tid >> 5;    // rgB in [0,8), 2 rows each
    float b0 = wp_ws_b[colB];
    float a0 = b0, a1 = b0;
    #pragma unroll 8
    for (int j = 0; j < 144; j++){
      int jj = (j < 128) ? j : (j + 16);
      float w = wp_ws_w[j*32 + colB];
      const float* xb = &XT[jj*XSTR_ + rgB*2];
      a0 = fmaf(xb[0], w, a0);
      a1 = fmaf(xb[1], w, a1);
    }
    // rows row0 + rgB*2 + {0,1}; row0 multiple of 16 -> c = k, n = row0/2+rgB
    const int n = (row0 >> 1) + rgB;
    pexp[(0*32 + colB)*N_ + n] = __expf(a0);      // c=0  (no max-sub: |l|<~8)
    pexp[(1*32 + colB)*N_ + n] = __expf(a1);      // c=1
  }
  __syncthreads();                                // XT dead; SIG live

  // phase 2c: sig/silu once from registers (new acc layout)
  #pragma unroll
  for (int k = 0; k < 4; k++){
    const int rr = rg4*4 + k;
    float so0 = acc[k][0], so1 = acc[k][1];
    float sg0 = sigm(so0), sg1 = sigm(so1);
    SIG[rr*128 + colP    ] = sg0;
    SIG[rr*128 + colP + 1] = sg1;
    SO [rr*128 + colP    ] = so0 * sg0;           // silu
    SO [rr*128 + colP + 1] = so1 * sg1;
  }
  __syncthreads();

  // phase 3: gate = sigmoid(sig_so @ q_wsv_w + b)  (16 rows x 16 = 256 thr)
  {
    const int r = tid >> 4, g = tid & 15;
    float ga = q_wsv_b[g];
    #pragma unroll 8
    for (int o = 0; o < 128; o += 4){
      float4 s4 = *(const float4*)&SIG[r*128 + o];
      ga = fmaf(s4.x, q_wsv_w[(o+0)*16 + g], ga);
      ga = fmaf(s4.y, q_wsv_w[(o+1)*16 + g], ga);
      ga = fmaf(s4.z, q_wsv_w[(o+2)*16 + g], ga);
      ga = fmaf(s4.w, q_wsv_w[(o+3)*16 + g], ga);
    }
    GATE[r*16 + g] = sigm(ga);
  }
  __syncthreads();

  // phase 4 (64 items) + phase 5 (768 items) combined strided loop
  for (int t = tid; t < 64 + ROWS_*48; t += 256){
    if (t < 64){
      // eq[h] = silu_so_head . ws_q   (16 rows x 4 h)
      const int r = t >> 2, h = t & 3;
      float e = 0.f;
      #pragma unroll
      for (int u = 0; u < 32; u++)
        e = fmaf(SO[r*128 + h*32 + u], attn_ws_w[u], e);
      eqh[(row0 + r)*100 + h] = e;
    } else {
      // qv = (vh_q @ q_wv)^T * gate   (16*48 = 768 work items)
      const int t2 = t - 64;
      int r = t2 / 48, k = t2 - r*48, i = k / 3, d = k - i*3;
      float a = 0.f;
      #pragma unroll
      for (int j = 0; j < 16; j++)
        a = fmaf(VHQ[r*48 + d*16 + j], q_wv[j*16 + i], a);
      QV[r*48 + k] = a * GATE[r*16 + i];
    }
  }
  __syncthreads();

  // phase 6: qh[h][d][e] = sum_i qv[h*4+i][d] * wh_q[i][e]  (16*96 = 1536)
  for (int t = tid; t < ROWS_*96; t += 256){
    int r = t / 96, k = t - r*96;
    int h = k / 24, rem = k - h*24, d = rem >> 3, ee = rem & 7;
    float a = 0.f;
    #pragma unroll
    for (int i = 0; i < 4; i++)
      a = fmaf(QV[r*48 + (h*4 + i)*3 + d], attn_wh[i*8 + ee], a);
    eqh[(row0 + r)*100 + 8 + k] = a;
  }
}

// ===== kAccum: weighted sums via atomics, 800 blocks (R13/R19 exact) =======
__global__ __launch_bounds__(256) void kAccum(const float* __restrict__ pexp,
                                              fptr s, fptr v,
                                              float* __restrict__ sg)
{
  const int b = blockIdx.x;
  const int c = b & 1, ah = (b >> 1) & 1, chunk = b >> 2;
  const int n0 = chunk * 50;
  const int tid = threadIdx.x;
  const int ag = tid >> 6, dl = tid & 63;
  const int abase = ah*16 + ag*4;

  const float* pb = pexp + (c*32 + abase)*N_;
  float acc[4][3] = {};
  float dn[4] = {};

  #pragma unroll 2
  for (int n = n0; n < n0 + 50; n++){
    const int rc = n*2 + c;
    float pw[4];
    #pragma unroll
    for (int aa = 0; aa < 4; aa++){
      pw[aa] = pb[aa*N_ + n];
      dn[aa] += pw[aa];
    }
    #pragma unroll
    for (int dd = 0; dd < 3; dd++){
      int d = dl + 64*dd;
      if (d < 176){
        float xv = (d < 128) ? s[rc*128 + d] : v[rc*48 + d - 128];
        #pragma unroll
        for (int aa = 0; aa < 4; aa++)
          acc[aa][dd] = fmaf(pw[aa], xv, acc[aa][dd]);
      }
    }
  }
  #pragma unroll
  for (int aa = 0; aa < 4; aa++){
    const int base = (c*32 + abase + aa)*SGSTRIDE_;
    #pragma unroll
    for (int dd = 0; dd < 3; dd++){
      int d = dl + 64*dd;
      if (d < 176) atomicAdd(&sg[base + d], acc[aa][dd]);
    }
    if (dl == 0) atomicAdd(&sg[base + 176], dn[aa]);
  }
}

// ================= kSmall: normalize + k/vv GVP + attn tables ===============
__global__ __launch_bounds__(256) void kSmall(
    const float* __restrict__ sg,
    fptr k_wh, fptr k_ws_w, fptr k_ws_b, fptr k_wv, fptr k_wsv_w, fptr k_wsv_b,
    fptr vv_wh, fptr vv_ws_w, fptr vv_ws_b, fptr vv_wv, fptr vv_wsv_w, fptr vv_wsv_b,
    fptr attn_wh, fptr attn_ws_w,
    float* __restrict__ tkh, float* __restrict__ tek,
    float* __restrict__ tvs, float* __restrict__ tvv)
{
  const int b = blockIdx.x, r = b >> 1, c = b & 1;
  const int tid = threadIdx.x;
  __shared__ float X[176];
  __shared__ float VN[2][16];
  __shared__ float VH[2][48];
  __shared__ float SOk[128], SOv[128];
  __shared__ float G[2][16];
  __shared__ float KV[48];

  if (tid < 176){
    const float* p = sg + (c*32 + r)*SGSTRIDE_;
    X[tid] = p[tid] / p[176];
  }
  __syncthreads();

  if (tid < 32){
    int path = tid >> 4, i = tid & 15;
    fptr wh = path ? vv_wh : k_wh;
    float h0=0.f, h1=0.f, h2=0.f;
    #pragma unroll
    for (int j = 0; j < 16; j++){
      float w = wh[j*16 + i];
      h0 = fmaf(X[128 + j*3 + 0], w, h0);
      h1 = fmaf(X[128 + j*3 + 1], w, h1);
      h2 = fmaf(X[128 + j*3 + 2], w, h2);
    }
    VH[path][ 0 + i] = h0; VH[path][16 + i] = h1; VH[path][32 + i] = h2;
    VN[path][i] = sqrtf(fmaxf(h0*h0 + h1*h1 + h2*h2, 1e-8f));
  }
  __syncthreads();

  {
    int path = tid >> 7, col = tid & 127;
    fptr W  = path ? vv_ws_w : k_ws_w;
    fptr Bb = path ? vv_ws_b : k_ws_b;
    float so = Bb[col];
    for (int j = 0; j < 128; j++) so = fmaf(X[j], W[j*128 + col], so);
    #pragma unroll
    for (int i = 0; i < 16; i++)  so = fmaf(VN[path][i], W[(128+i)*128 + col], so);
    (path ? SOv : SOk)[col] = so;
  }
  __syncthreads();

  if (tid < 32){
    int path = tid >> 4, g = tid & 15;
    fptr Wsv = path ? vv_wsv_w : k_wsv_w;
    fptr Bsv = path ? vv_wsv_b : k_wsv_b;
    const float* SOp = path ? SOv : SOk;
    float ga = Bsv[g];
    for (int o = 0; o < 128; o++)
      ga = fmaf(sigm(SOp[o]), Wsv[o*16 + g], ga);
    G[path][g] = sigm(ga);
  } else if (tid < 36){
    int h = tid - 32;
    float e = 0.f;
    #pragma unroll
    for (int t = 0; t < 32; t++){
      float so = SOk[h*32 + t];
      e = fmaf(so * sigm(so), attn_ws_w[32 + t], e);
    }
    tek[(r*2 + c)*4 + h] = e;
  } else if (tid >= 64 && tid < 192){
    int o = tid - 64;
    float so = SOv[o];
    tvs[(r*2 + c)*128 + o] = so * sigm(so);
  }
  __syncthreads();

  if (tid < 96){
    int path = tid / 48, k = tid % 48, i = k / 3, d = k - i*3;
    fptr Wv = path ? vv_wv : k_wv;
    float vo = 0.f;
    #pragma unroll
    for (int j = 0; j < 16; j++)
      vo = fmaf(VH[path][d*16 + j], Wv[j*16 + i], vo);
    float gv = vo * G[path][i];
    if (path == 0) KV[k] = gv;
    else {
      int h = i >> 2, ii = i & 3;
      tvv[(((r*2 + c)*4 + h)*4 + ii)*3 + d] = gv;
    }
  }
  __syncthreads();

  if (tid < 96){
    int h = tid / 24, rem = tid % 24, d = rem >> 3, ee = rem & 7;
    float a = 0.f;
    #pragma unroll
    for (int i = 0; i < 4; i++)
      a = fmaf(KV[(h*4 + i)*3 + d], attn_wh[(4 + i)*8 + ee], a);
    tkh[((r*2 + c)*4 + h)*24 + d*8 + ee] = a;
  }
}

// ================= kAttn (R19): block = 64 rows x one h ====================
__global__ __launch_bounds__(256) void kAttn(
    const float* __restrict__ eqh,
    const float* __restrict__ tkh, const float* __restrict__ tek,
    const float* __restrict__ tvs, const float* __restrict__ tvv,
    fptr attn_ws_w, fptr attn_ws_b,
    float* __restrict__ out)
{
  __shared__ __align__(16) float KH[64*28];
  __shared__ __align__(16) float VS[64*36];
  __shared__ __align__(16) float VV[64*12];
  __shared__ float EK[64];
  const int tid = threadIdx.x;
  const int h      = blockIdx.x & 3;
  const int rowblk = blockIdx.x >> 2;

  for (int i = tid; i < 64*24; i += 256){
    int m = i / 24, t = i - m*24;
    KH[m*28 + t] = tkh[(m*4 + h)*24 + t];
  }
  for (int i = tid; i < 64*32; i += 256){
    int m = i >> 5, t = i & 31;
    VS[m*36 + t] = tvs[m*128 + h*32 + t];
  }
  for (int i = tid; i < 64*12; i += 256){
    int m = i / 12, t = i - m*12;
    VV[m*12 + t] = tvv[(m*4 + h)*12 + t];
  }
  if (tid < 64) EK[tid] = tek[tid*4 + h];

  float wsn[8];
  #pragma unroll
  for (int ee = 0; ee < 8; ee++) wsn[ee] = attn_ws_w[64 + ee];
  const float wb = attn_ws_b[0];
  __syncthreads();

  const int rh  = tid & 3;
  const int row = rowblk*64 + (tid >> 2);
  if (row < NC_){
    const int c = row & 1;
    const float eq = eqh[row*100 + h];
    float qh[24];
    {
      const float4* qp = (const float4*)&eqh[row*100 + 8 + h*24];
      #pragma unroll
      for (int k = 0; k < 6; k++){
        float4 t4 = qp[k];
        qh[k*4+0] = t4.x; qh[k*4+1] = t4.y; qh[k*4+2] = t4.z; qh[k*4+3] = t4.w;
      }
    }
    float4 accs4[8];
    float4 accv4[3];
    #pragma unroll
    for (int q = 0; q < 8; q++) accs4[q] = make_float4(0.f,0.f,0.f,0.f);
    #pragma unroll
    for (int q = 0; q < 3; q++) accv4[q] = make_float4(0.f,0.f,0.f,0.f);
    float den = 0.f;

    #pragma unroll
    for (int rr = 0; rr < 8; rr++){
      const int m = (rh*8 + rr)*2 + c;
      const float* khp = &KH[m*28];
      float en = 0.f;
      #pragma unroll
      for (int ee = 0; ee < 8; ee++){
        float a0 = qh[ee]      + khp[ee];
        float a1 = qh[8 + ee]  + khp[8 + ee];
        float a2 = qh[16 + ee] + khp[16 + ee];
        en = fmaf(sqrtf(fmaxf(a0*a0 + a1*a1 + a2*a2, 1e-8f)), wsn[ee], en);
      }
      const float w = __expf((eq + EK[m] + en + wb) * 0.17677669529663687f);
      den += w;
      const float4* vp4 = (const float4*)&VS[m*36];
      #pragma unroll
      for (int q = 0; q < 8; q++){
        float4 t4 = vp4[q];
        accs4[q].x = fmaf(w, t4.x, accs4[q].x);
        accs4[q].y = fmaf(w, t4.y, accs4[q].y);
        accs4[q].z = fmaf(w, t4.z, accs4[q].z);
        accs4[q].w = fmaf(w, t4.w, accs4[q].w);
      }
      const float4* vv4 = (const float4*)&VV[m*12];
      #pragma unroll
      for (int q = 0; q < 3; q++){
        float4 t4 = vv4[q];
        accv4[q].x = fmaf(w, t4.x, accv4[q].x);
        accv4[q].y = fmaf(w, t4.y, accv4[q].y);
        accv4[q].z = fmaf(w, t4.z, accv4[q].z);
        accv4[q].w = fmaf(w, t4.w, accv4[q].w);
      }
    }

    #pragma unroll
    for (int q = 0; q < 8; q++){
      accs4[q].x += __shfl_xor(accs4[q].x, 1, 64);
      accs4[q].x += __shfl_xor(accs4[q].x, 2, 64);
      accs4[q].y += __shfl_xor(accs4[q].y, 1, 64);
      accs4[q].y += __shfl_xor(accs4[q].y, 2, 64);
      accs4[q].z += __shfl_xor(accs4[q].z, 1, 64);
      accs4[q].z += __shfl_xor(accs4[q].z, 2, 64);
      accs4[q].w += __shfl_xor(accs4[q].w, 1, 64);
      accs4[q].w += __shfl_xor(accs4[q].w, 2, 64);
    }
    #pragma unroll
    for (int q = 0; q < 3; q++){
      accv4[q].x += __shfl_xor(accv4[q].x, 1, 64);
      accv4[q].x += __shfl_xor(accv4[q].x, 2, 64);
      accv4[q].y += __shfl_xor(accv4[q].y, 1, 64);
      accv4[q].y += __shfl_xor(accv4[q].y, 2, 64);
      accv4[q].z += __shfl_xor(accv4[q].z, 1, 64);
      accv4[q].z += __shfl_xor(accv4[q].z, 2, 64);
      accv4[q].w += __shfl_xor(accv4[q].w, 1, 64);
      accv4[q].w += __shfl_xor(accv4[q].w, 2, 64);
    }
    den += __shfl_xor(den, 1, 64);
    den += __shfl_xor(den, 2, 64);

    if (rh == 0){
      const float inv = 1.f / den;
      float4* po = (float4*)&out[row*128 + h*32];
      #pragma unroll
      for (int q = 0; q < 8; q++){
        float4 t4 = accs4[q];
        t4.x *= inv; t4.y *= inv; t4.z *= inv; t4.w *= inv;
        po[q] = t4;
      }
      float4* pv = (float4*)&out[NC_*128 + row*48 + h*12];
      #pragma unroll
      for (int q = 0; q < 3; q++){
        float4 t4 = accv4[q];
        t4.x *= inv; t4.y *= inv; t4.z *= inv; t4.w *= inv;
        pv[q] = t4;
      }
    }
  }
}

extern "C" void kernel_launch(void* const* d_in, const int* in_sizes, int n_in,
                              void* d_out, int out_size, void* d_ws, size_t ws_size,
                              hipStream_t stream)
{
  fptr s        = (fptr)d_in[0];
  fptr v        = (fptr)d_in[1];
  fptr wp_wh    = (fptr)d_in[2];
  fptr wp_ws_w  = (fptr)d_in[3];
  fptr wp_ws_b  = (fptr)d_in[4];
  fptr q_wh     = (fptr)d_in[5];
  fptr q_ws_w   = (fptr)d_in[6];
  fptr q_ws_b   = (fptr)d_in[7];
  fptr q_wv     = (fptr)d_in[8];
  fptr q_wsv_w  = (fptr)d_in[9];
  fptr q_wsv_b  = (fptr)d_in[10];
  fptr k_wh     = (fptr)d_in[11];
  fptr k_ws_w   = (fptr)d_in[12];
  fptr k_ws_b   = (fptr)d_in[13];
  fptr k_wv     = (fptr)d_in[14];
  fptr k_wsv_w  = (fptr)d_in[15];
  fptr k_wsv_b  = (fptr)d_in[16];
  fptr vv_wh    = (fptr)d_in[17];
  fptr vv_ws_w  = (fptr)d_in[18];
  fptr vv_ws_b  = (fptr)d_in[19];
  fptr vv_wv    = (fptr)d_in[20];
  fptr vv_wsv_w = (fptr)d_in[21];
  fptr vv_wsv_b = (fptr)d_in[22];
  fptr attn_wh  = (fptr)d_in[23];
  fptr attn_ws_w= (fptr)d_in[24];
  fptr attn_ws_b= (fptr)d_in[25];

  float* ws   = (float*)d_ws;
  float* pexp = ws + OFF_LG;
  float* eqh  = ws + OFF_EQH;
  float* sg   = ws + OFF_SG;
  float* tkh  = ws + OFF_TKH;
  float* tek  = ws + OFF_TEK;
  float* tvs  = ws + OFF_TVS;
  float* tvv  = ws + OFF_TVV;

  kA<<<NC_/ROWS_, 256, 0, stream>>>(s, v, wp_wh, wp_ws_w, wp_ws_b,
                                    q_wh, q_ws_w, q_ws_b, q_wv, q_wsv_w, q_wsv_b,
                                    attn_wh, attn_ws_w, pexp, eqh, sg);
  kAccum<<<800, 256, 0, stream>>>(pexp, s, v, sg);
  kSmall<<<64, 256, 0, stream>>>(sg,
                                 k_wh, k_ws_w, k_ws_b, k_wv, k_wsv_w, k_wsv_b,
                                 vv_wh, vv_ws_w, vv_ws_b, vv_wv, vv_wsv_w, vv_wsv_b,
                                 attn_wh, attn_ws_w, tkh, tek, tvs, tvv);
  kAttn<<<((NC_ + 63)/64)*4, 256, 0, stream>>>(eqh, tkh, tek, tvs, tvv,
                                               attn_ws_w, attn_ws_b, (float*)d_out);
}

// Round 12
// 231.637 us; speedup vs baseline: 1.0444x; 1.0235x over previous
//
#include <hip/hip_runtime.h>
#include <hip/hip_bf16.h>

// GVPDynamicProjection: N=10000, C=2, SI=128, VI=16, H=4, R=32, SH=32, VH=4
// R25 = exact R19 configuration (verified best, 233.9us): kA = R16 body
// (R24's half-broadcast 2a falsified the DS model: 51us, no gain -> kA's
// ~47us is a multi-pipe structural floor after SIX failed phase-2 rewrites),
// kAccum = 800-block atomics (R22/R23 proved atomics near-free), kSmall
// unchanged, kAttn = R19 64-rows-x-one-h (the session's one clear win,
// 43 -> ~18us). Remaining budget: fill 43us (harness re-poison at HBM
// roofline) + ~120us re-poison/launch overhead outside kernel control.

#define N_  10000
#define C_  2
#define SI_ 128
#define VI_ 16
#define H_  4
#define R_  32
#define SH_ 32
#define VH_ 4
#define NC_ (N_*C_)

#define ROWS_ 16
#define XSTR_ 20   // XT leading stride: 16 rows + 4 pad; 80B = 5x16B aligned

typedef const float* __restrict__ fptr;

__device__ __forceinline__ float sigm(float x){ return 1.f/(1.f+__expf(-x)); }

// ---------------- ws layout (float offsets) ----------------
// pexp : [C_*32][N_]   exp(logits), TRANSPOSED      640000
// eqh  : [NC_][100]    per-row eq[4] @0, qh[96] @8  2000000
// sg   : [64][180]     sums: d<176 = sum e^l*x, 176 = sum e^l (zeroed by kA blk0)
// tkh/tek/tvs/tvv: attn tables
#define OFF_LG   0
#define OFF_EQH  640000
#define OFF_SG   2640000
#define OFF_TKH  2651520
#define OFF_TEK  2657664
#define OFF_TVS  2657920
#define OFF_TVV  2666112

#define SGSTRIDE_ 180

// ================= kernel A: per-row logits + q-path (R16 exact) ===========
// 256 threads, 16 rows/block; grid = NC_/16 = 1250; ~30.5KB LDS -> 5 blk/CU
__global__ __launch_bounds__(256) void kA(
    fptr s, fptr v,
    fptr wp_wh, fptr wp_ws_w, fptr wp_ws_b,
    fptr q_wh, fptr q_ws_w, fptr q_ws_b, fptr q_wv, fptr q_wsv_w, fptr q_wsv_b,
    fptr attn_wh, fptr attn_ws_w,
    float* __restrict__ pexp, float* __restrict__ eqh,
    float* __restrict__ sgz)
{
  // ARENA: phase 0-2 = XT transposed [j][row], stride 20 (16B-aligned:
  //        j*80B = 5x16B; rgA*8 floats = 32B)
  //        j: 0..127 = s, 128..143 = vn_q, 144..159 = vn_p
  //        phase 2c+ = SIG [16][128] (2048 <= 3200), aliases dead XT
  __shared__ __align__(16) float ARENA[160*XSTR_];
  __shared__ __align__(16) float VVs[ROWS_*48];
  __shared__ __align__(16) float VHQ[ROWS_*48];
  __shared__ __align__(16) float SO[ROWS_*128];
  __shared__ __align__(16) float GATE[ROWS_*16];
  __shared__ __align__(16) float QV[ROWS_*48];
  float* const XT  = ARENA;
  float* const SIG = ARENA;

  const int tid  = threadIdx.x;
  const int row0 = blockIdx.x * ROWS_;

  // block 0 also zeroes sg (kAccum is stream-ordered after all kA blocks)
  if (blockIdx.x == 0){
    for (int i = tid; i < 64*SGSTRIDE_; i += 256) sgz[i] = 0.f;
  }

  // phase 0: stage s, v
  for (int idx = tid; idx < ROWS_*128; idx += 256){
    int r = idx >> 7, j = idx & 127;
    XT[j*XSTR_ + r] = s[(row0+r)*128 + j];
  }
  for (int idx = tid; idx < ROWS_*48; idx += 256){
    int r = idx / 48, k = idx - r*48;
    VVs[r*48 + k] = v[(row0+r)*48 + k];
  }
  __syncthreads();

  // phase 1: vh / vn, 16 rows x 32 (path,i) = 512 work items
  for (int idx = tid; idx < ROWS_*32; idx += 256){
    int r = idx >> 5, ii = idx & 31, path = ii >> 4, i = ii & 15;
    fptr wh = path ? wp_wh : q_wh;
    float h0=0.f, h1=0.f, h2=0.f;
    #pragma unroll
    for (int j = 0; j < 16; j++){
      float w = wh[j*16 + i];
      h0 = fmaf(VVs[r*48 + j*3 + 0], w, h0);
      h1 = fmaf(VVs[r*48 + j*3 + 1], w, h1);
      h2 = fmaf(VVs[r*48 + j*3 + 2], w, h2);
    }
    float vn = sqrtf(fmaxf(h0*h0 + h1*h1 + h2*h2, 1e-8f));
    if (!path){
      VHQ[r*48 +  0 + i] = h0;
      VHQ[r*48 + 16 + i] = h1;
      VHQ[r*48 + 32 + i] = h2;
      XT[(128+i)*XSTR_ + r] = vn;
    } else {
      XT[(144+i)*XSTR_ + r] = vn;
    }
  }
  __syncthreads();

  // phase 2a: so = [s, vn_q] @ q_ws_w + b  (128 cols x 2 rowgroups of 8 rows)
  const int colA = tid & 127, rgA = tid >> 7;   // rgA in {0,1}, 8 rows each
  float acc[8];
  {
    float bqs = q_ws_b[colA];
    #pragma unroll
    for (int k = 0; k < 8; k++) acc[k] = bqs;
    const float* xbA = &XT[rgA*8];
    #pragma unroll 8
    for (int j = 0; j < 144; j++){
      float w = q_ws_w[j*128 + colA];             // coalesced 64-consec/wave
      const float* xb = xbA + j*XSTR_;
      float4 x0 = *(const float4*)(xb + 0);       // wave-uniform broadcast
      float4 x1 = *(const float4*)(xb + 4);
      acc[0] = fmaf(x0.x, w, acc[0]); acc[1] = fmaf(x0.y, w, acc[1]);
      acc[2] = fmaf(x0.z, w, acc[2]); acc[3] = fmaf(x0.w, w, acc[3]);
      acc[4] = fmaf(x1.x, w, acc[4]); acc[5] = fmaf(x1.y, w, acc[5]);
      acc[6] = fmaf(x1.z, w, acc[6]); acc[7] = fmaf(x1.w, w, acc[7]);
    }
  }
  // phase 2b: logits -> store EXP(logit), TRANSPOSED pexp[(c*32+a)][n]
  // 32 cols x 8 rowgroups of 2 rows
  {
    const int colB = tid & 31, rgB = tid >> 5;    // rgB in [0,8), 2 rows each
    float b0 = wp_ws_b[colB];
    float a0 = b0, a1 = b0;
    #pragma unroll 8
    for (int j = 0; j < 144; j++){
      int jj = (j < 128) ? j : (j + 16);
      float w = wp_ws_w[j*32 + colB];
      const float* xb = &XT[jj*XSTR_ + rgB*2];
      a0 = fmaf(xb[0], w, a0);
      a1 = fmaf(xb[1], w, a1);
    }
    // rows row0 + rgB*2 + {0,1}; row0 multiple of 16 -> c = k, n = row0/2+rgB
    const int n = (row0 >> 1) + rgB;
    pexp[(0*32 + colB)*N_ + n] = __expf(a0);      // c=0  (no max-sub: |l|<~8)
    pexp[(1*32 + colB)*N_ + n] = __expf(a1);      // c=1
  }
  __syncthreads();                                // XT dead; SIG live

  // phase 2c: sig/silu once from registers
  #pragma unroll
  for (int k = 0; k < 8; k++){
    float so = acc[k];
    float sg_ = sigm(so);
    SIG[(rgA*8 + k)*128 + colA] = sg_;
    SO [(rgA*8 + k)*128 + colA] = so * sg_;       // silu
  }
  __syncthreads();

  // phase 3: gate = sigmoid(sig_so @ q_wsv_w + b)  (16 rows x 16 = 256 thr)
  {
    const int r = tid >> 4, g = tid & 15;
    float ga = q_wsv_b[g];
    #pragma unroll 8
    for (int o = 0; o < 128; o += 4){
      float4 s4 = *(const float4*)&SIG[r*128 + o];
      ga = fmaf(s4.x, q_wsv_w[(o+0)*16 + g], ga);
      ga = fmaf(s4.y, q_wsv_w[(o+1)*16 + g], ga);
      ga = fmaf(s4.z, q_wsv_w[(o+2)*16 + g], ga);
      ga = fmaf(s4.w, q_wsv_w[(o+3)*16 + g], ga);
    }
    GATE[r*16 + g] = sigm(ga);
  }
  __syncthreads();

  // phase 4 (64 items) + phase 5 (768 items) combined strided loop
  for (int t = tid; t < 64 + ROWS_*48; t += 256){
    if (t < 64){
      // eq[h] = silu_so_head . ws_q   (16 rows x 4 h)
      const int r = t >> 2, h = t & 3;
      float e = 0.f;
      #pragma unroll
      for (int u = 0; u < 32; u++)
        e = fmaf(SO[r*128 + h*32 + u], attn_ws_w[u], e);
      eqh[(row0 + r)*100 + h] = e;
    } else {
      // qv = (vh_q @ q_wv)^T * gate   (16*48 = 768 work items)
      const int t2 = t - 64;
      int r = t2 / 48, k = t2 - r*48, i = k / 3, d = k - i*3;
      float a = 0.f;
      #pragma unroll
      for (int j = 0; j < 16; j++)
        a = fmaf(VHQ[r*48 + d*16 + j], q_wv[j*16 + i], a);
      QV[r*48 + k] = a * GATE[r*16 + i];
    }
  }
  __syncthreads();

  // phase 6: qh[h][d][e] = sum_i qv[h*4+i][d] * wh_q[i][e]  (16*96 = 1536)
  for (int t = tid; t < ROWS_*96; t += 256){
    int r = t / 96, k = t - r*96;
    int h = k / 24, rem = k - h*24, d = rem >> 3, ee = rem & 7;
    float a = 0.f;
    #pragma unroll
    for (int i = 0; i < 4; i++)
      a = fmaf(QV[r*48 + (h*4 + i)*3 + d], attn_wh[i*8 + ee], a);
    eqh[(row0 + r)*100 + 8 + k] = a;
  }
}

// ===== kAccum: weighted sums via atomics, 800 blocks (R13/R19 exact) =======
__global__ __launch_bounds__(256) void kAccum(const float* __restrict__ pexp,
                                              fptr s, fptr v,
                                              float* __restrict__ sg)
{
  const int b = blockIdx.x;
  const int c = b & 1, ah = (b >> 1) & 1, chunk = b >> 2;
  const int n0 = chunk * 50;
  const int tid = threadIdx.x;
  const int ag = tid >> 6, dl = tid & 63;
  const int abase = ah*16 + ag*4;

  const float* pb = pexp + (c*32 + abase)*N_;
  float acc[4][3] = {};
  float dn[4] = {};

  #pragma unroll 2
  for (int n = n0; n < n0 + 50; n++){
    const int rc = n*2 + c;
    float pw[4];
    #pragma unroll
    for (int aa = 0; aa < 4; aa++){
      pw[aa] = pb[aa*N_ + n];
      dn[aa] += pw[aa];
    }
    #pragma unroll
    for (int dd = 0; dd < 3; dd++){
      int d = dl + 64*dd;
      if (d < 176){
        float xv = (d < 128) ? s[rc*128 + d] : v[rc*48 + d - 128];
        #pragma unroll
        for (int aa = 0; aa < 4; aa++)
          acc[aa][dd] = fmaf(pw[aa], xv, acc[aa][dd]);
      }
    }
  }
  #pragma unroll
  for (int aa = 0; aa < 4; aa++){
    const int base = (c*32 + abase + aa)*SGSTRIDE_;
    #pragma unroll
    for (int dd = 0; dd < 3; dd++){
      int d = dl + 64*dd;
      if (d < 176) atomicAdd(&sg[base + d], acc[aa][dd]);
    }
    if (dl == 0) atomicAdd(&sg[base + 176], dn[aa]);
  }
}

// ================= kSmall: normalize + k/vv GVP + attn tables ===============
__global__ __launch_bounds__(256) void kSmall(
    const float* __restrict__ sg,
    fptr k_wh, fptr k_ws_w, fptr k_ws_b, fptr k_wv, fptr k_wsv_w, fptr k_wsv_b,
    fptr vv_wh, fptr vv_ws_w, fptr vv_ws_b, fptr vv_wv, fptr vv_wsv_w, fptr vv_wsv_b,
    fptr attn_wh, fptr attn_ws_w,
    float* __restrict__ tkh, float* __restrict__ tek,
    float* __restrict__ tvs, float* __restrict__ tvv)
{
  const int b = blockIdx.x, r = b >> 1, c = b & 1;
  const int tid = threadIdx.x;
  __shared__ float X[176];
  __shared__ float VN[2][16];
  __shared__ float VH[2][48];
  __shared__ float SOk[128], SOv[128];
  __shared__ float G[2][16];
  __shared__ float KV[48];

  if (tid < 176){
    const float* p = sg + (c*32 + r)*SGSTRIDE_;
    X[tid] = p[tid] / p[176];
  }
  __syncthreads();

  if (tid < 32){
    int path = tid >> 4, i = tid & 15;
    fptr wh = path ? vv_wh : k_wh;
    float h0=0.f, h1=0.f, h2=0.f;
    #pragma unroll
    for (int j = 0; j < 16; j++){
      float w = wh[j*16 + i];
      h0 = fmaf(X[128 + j*3 + 0], w, h0);
      h1 = fmaf(X[128 + j*3 + 1], w, h1);
      h2 = fmaf(X[128 + j*3 + 2], w, h2);
    }
    VH[path][ 0 + i] = h0; VH[path][16 + i] = h1; VH[path][32 + i] = h2;
    VN[path][i] = sqrtf(fmaxf(h0*h0 + h1*h1 + h2*h2, 1e-8f));
  }
  __syncthreads();

  {
    int path = tid >> 7, col = tid & 127;
    fptr W  = path ? vv_ws_w : k_ws_w;
    fptr Bb = path ? vv_ws_b : k_ws_b;
    float so = Bb[col];
    for (int j = 0; j < 128; j++) so = fmaf(X[j], W[j*128 + col], so);
    #pragma unroll
    for (int i = 0; i < 16; i++)  so = fmaf(VN[path][i], W[(128+i)*128 + col], so);
    (path ? SOv : SOk)[col] = so;
  }
  __syncthreads();

  if (tid < 32){
    int path = tid >> 4, g = tid & 15;
    fptr Wsv = path ? vv_wsv_w : k_wsv_w;
    fptr Bsv = path ? vv_wsv_b : k_wsv_b;
    const float* SOp = path ? SOv : SOk;
    float ga = Bsv[g];
    for (int o = 0; o < 128; o++)
      ga = fmaf(sigm(SOp[o]), Wsv[o*16 + g], ga);
    G[path][g] = sigm(ga);
  } else if (tid < 36){
    int h = tid - 32;
    float e = 0.f;
    #pragma unroll
    for (int t = 0; t < 32; t++){
      float so = SOk[h*32 + t];
      e = fmaf(so * sigm(so), attn_ws_w[32 + t], e);
    }
    tek[(r*2 + c)*4 + h] = e;
  } else if (tid >= 64 && tid < 192){
    int o = tid - 64;
    float so = SOv[o];
    tvs[(r*2 + c)*128 + o] = so * sigm(so);
  }
  __syncthreads();

  if (tid < 96){
    int path = tid / 48, k = tid % 48, i = k / 3, d = k - i*3;
    fptr Wv = path ? vv_wv : k_wv;
    float vo = 0.f;
    #pragma unroll
    for (int j = 0; j < 16; j++)
      vo = fmaf(VH[path][d*16 + j], Wv[j*16 + i], vo);
    float gv = vo * G[path][i];
    if (path == 0) KV[k] = gv;
    else {
      int h = i >> 2, ii = i & 3;
      tvv[(((r*2 + c)*4 + h)*4 + ii)*3 + d] = gv;
    }
  }
  __syncthreads();

  if (tid < 96){
    int h = tid / 24, rem = tid % 24, d = rem >> 3, ee = rem & 7;
    float a = 0.f;
    #pragma unroll
    for (int i = 0; i < 4; i++)
      a = fmaf(KV[(h*4 + i)*3 + d], attn_wh[(4 + i)*8 + ee], a);
    tkh[((r*2 + c)*4 + h)*24 + d*8 + ee] = a;
  }
}

// ================= kAttn (R19): block = 64 rows x one h ====================
__global__ __launch_bounds__(256) void kAttn(
    const float* __restrict__ eqh,
    const float* __restrict__ tkh, const float* __restrict__ tek,
    const float* __restrict__ tvs, const float* __restrict__ tvv,
    fptr attn_ws_w, fptr attn_ws_b,
    float* __restrict__ out)
{
  __shared__ __align__(16) float KH[64*28];
  __shared__ __align__(16) float VS[64*36];
  __shared__ __align__(16) float VV[64*12];
  __shared__ float EK[64];
  const int tid = threadIdx.x;
  const int h      = blockIdx.x & 3;
  const int rowblk = blockIdx.x >> 2;

  for (int i = tid; i < 64*24; i += 256){
    int m = i / 24, t = i - m*24;
    KH[m*28 + t] = tkh[(m*4 + h)*24 + t];
  }
  for (int i = tid; i < 64*32; i += 256){
    int m = i >> 5, t = i & 31;
    VS[m*36 + t] = tvs[m*128 + h*32 + t];
  }
  for (int i = tid; i < 64*12; i += 256){
    int m = i / 12, t = i - m*12;
    VV[m*12 + t] = tvv[(m*4 + h)*12 + t];
  }
  if (tid < 64) EK[tid] = tek[tid*4 + h];

  float wsn[8];
  #pragma unroll
  for (int ee = 0; ee < 8; ee++) wsn[ee] = attn_ws_w[64 + ee];
  const float wb = attn_ws_b[0];
  __syncthreads();

  const int rh  = tid & 3;
  const int row = rowblk*64 + (tid >> 2);
  if (row < NC_){
    const int c = row & 1;
    const float eq = eqh[row*100 + h];
    float qh[24];
    {
      const float4* qp = (const float4*)&eqh[row*100 + 8 + h*24];
      #pragma unroll
      for (int k = 0; k < 6; k++){
        float4 t4 = qp[k];
        qh[k*4+0] = t4.x; qh[k*4+1] = t4.y; qh[k*4+2] = t4.z; qh[k*4+3] = t4.w;
      }
    }
    float4 accs4[8];
    float4 accv4[3];
    #pragma unroll
    for (int q = 0; q < 8; q++) accs4[q] = make_float4(0.f,0.f,0.f,0.f);
    #pragma unroll
    for (int q = 0; q < 3; q++) accv4[q] = make_float4(0.f,0.f,0.f,0.f);
    float den = 0.f;

    #pragma unroll
    for (int rr = 0; rr < 8; rr++){
      const int m = (rh*8 + rr)*2 + c;
      const float* khp = &KH[m*28];
      float en = 0.f;
      #pragma unroll
      for (int ee = 0; ee < 8; ee++){
        float a0 = qh[ee]      + khp[ee];
        float a1 = qh[8 + ee]  + khp[8 + ee];
        float a2 = qh[16 + ee] + khp[16 + ee];
        en = fmaf(sqrtf(fmaxf(a0*a0 + a1*a1 + a2*a2, 1e-8f)), wsn[ee], en);
      }
      const float w = __expf((eq + EK[m] + en + wb) * 0.17677669529663687f);
      den += w;
      const float4* vp4 = (const float4*)&VS[m*36];
      #pragma unroll
      for (int q = 0; q < 8; q++){
        float4 t4 = vp4[q];
        accs4[q].x = fmaf(w, t4.x, accs4[q].x);
        accs4[q].y = fmaf(w, t4.y, accs4[q].y);
        accs4[q].z = fmaf(w, t4.z, accs4[q].z);
        accs4[q].w = fmaf(w, t4.w, accs4[q].w);
      }
      const float4* vv4 = (const float4*)&VV[m*12];
      #pragma unroll
      for (int q = 0; q < 3; q++){
        float4 t4 = vv4[q];
        accv4[q].x = fmaf(w, t4.x, accv4[q].x);
        accv4[q].y = fmaf(w, t4.y, accv4[q].y);
        accv4[q].z = fmaf(w, t4.z, accv4[q].z);
        accv4[q].w = fmaf(w, t4.w, accv4[q].w);
      }
    }

    #pragma unroll
    for (int q = 0; q < 8; q++){
      accs4[q].x += __shfl_xor(accs4[q].x, 1, 64);
      accs4[q].x += __shfl_xor(accs4[q].x, 2, 64);
      accs4[q].y += __shfl_xor(accs4[q].y, 1, 64);
      accs4[q].y += __shfl_xor(accs4[q].y, 2, 64);
      accs4[q].z += __shfl_xor(accs4[q].z, 1, 64);
      accs4[q].z += __shfl_xor(accs4[q].z, 2, 64);
      accs4[q].w += __shfl_xor(accs4[q].w, 1, 64);
      accs4[q].w += __shfl_xor(accs4[q].w, 2, 64);
    }
    #pragma unroll
    for (int q = 0; q < 3; q++){
      accv4[q].x += __shfl_xor(accv4[q].x, 1, 64);
      accv4[q].x += __shfl_xor(accv4[q].x, 2, 64);
      accv4[q].y += __shfl_xor(accv4[q].y, 1, 64);
      accv4[q].y += __shfl_xor(accv4[q].y, 2, 64);
      accv4[q].z += __shfl_xor(accv4[q].z, 1, 64);
      accv4[q].z += __shfl_xor(accv4[q].z, 2, 64);
      accv4[q].w += __shfl_xor(accv4[q].w, 1, 64);
      accv4[q].w += __shfl_xor(accv4[q].w, 2, 64);
    }
    den += __shfl_xor(den, 1, 64);
    den += __shfl_xor(den, 2, 64);

    if (rh == 0){
      const float inv = 1.f / den;
      float4* po = (float4*)&out[row*128 + h*32];
      #pragma unroll
      for (int q = 0; q < 8; q++){
        float4 t4 = accs4[q];
        t4.x *= inv; t4.y *= inv; t4.z *= inv; t4.w *= inv;
        po[q] = t4;
      }
      float4* pv = (float4*)&out[NC_*128 + row*48 + h*12];
      #pragma unroll
      for (int q = 0; q < 3; q++){
        float4 t4 = accv4[q];
        t4.x *= inv; t4.y *= inv; t4.z *= inv; t4.w *= inv;
        pv[q] = t4;
      }
    }
  }
}

extern "C" void kernel_launch(void* const* d_in, const int* in_sizes, int n_in,
                              void* d_out, int out_size, void* d_ws, size_t ws_size,
                              hipStream_t stream)
{
  fptr s        = (fptr)d_in[0];
  fptr v        = (fptr)d_in[1];
  fptr wp_wh    = (fptr)d_in[2];
  fptr wp_ws_w  = (fptr)d_in[3];
  fptr wp_ws_b  = (fptr)d_in[4];
  fptr q_wh     = (fptr)d_in[5];
  fptr q_ws_w   = (fptr)d_in[6];
  fptr q_ws_b   = (fptr)d_in[7];
  fptr q_wv     = (fptr)d_in[8];
  fptr q_wsv_w  = (fptr)d_in[9];
  fptr q_wsv_b  = (fptr)d_in[10];
  fptr k_wh     = (fptr)d_in[11];
  fptr k_ws_w   = (fptr)d_in[12];
  fptr k_ws_b   = (fptr)d_in[13];
  fptr k_wv     = (fptr)d_in[14];
  fptr k_wsv_w  = (fptr)d_in[15];
  fptr k_wsv_b  = (fptr)d_in[16];
  fptr vv_wh    = (fptr)d_in[17];
  fptr vv_ws_w  = (fptr)d_in[18];
  fptr vv_ws_b  = (fptr)d_in[19];
  fptr vv_wv    = (fptr)d_in[20];
  fptr vv_wsv_w = (fptr)d_in[21];
  fptr vv_wsv_b = (fptr)d_in[22];
  fptr attn_wh  = (fptr)d_in[23];
  fptr attn_ws_w= (fptr)d_in[24];
  fptr attn_ws_b= (fptr)d_in[25];

  float* ws   = (float*)d_ws;
  float* pexp = ws + OFF_LG;
  float* eqh  = ws + OFF_EQH;
  float* sg   = ws + OFF_SG;
  float* tkh  = ws + OFF_TKH;
  float* tek  = ws + OFF_TEK;
  float* tvs  = ws + OFF_TVS;
  float* tvv  = ws + OFF_TVV;

  kA<<<NC_/ROWS_, 256, 0, stream>>>(s, v, wp_wh, wp_ws_w, wp_ws_b,
                                    q_wh, q_ws_w, q_ws_b, q_wv, q_wsv_w, q_wsv_b,
                                    attn_wh, attn_ws_w, pexp, eqh, sg);
  kAccum<<<800, 256, 0, stream>>>(pexp, s, v, sg);
  kSmall<<<64, 256, 0, stream>>>(sg,
                                 k_wh, k_ws_w, k_ws_b, k_wv, k_wsv_w, k_wsv_b,
                                 vv_wh, vv_ws_w, vv_ws_b, vv_wv, vv_wsv_w, vv_wsv_b,
                                 attn_wh, attn_ws_w, tkh, tek, tvs, tvv);
  kAttn<<<((NC_ + 63)/64)*4, 256, 0, stream>>>(eqh, tkh, tek, tvs, tvv,
                                               attn_ws_w, attn_ws_b, (float*)d_out);
}